// Round 1
// baseline (601.810 us; speedup 1.0000x reference)
//
#include <hip/hip_runtime.h>

// ---------------------------------------------------------------------------
// MultiHeadAttention (B=1, N=2925, D_MODEL=1536, 12 heads x 128) on gfx950.
// Pipeline: convert/transpose -> fused QKV bf16-MFMA GEMM -> RMSNorm+3D RoPE
// -> flash attention (online softmax, MFMA) -> output GEMM.
// ---------------------------------------------------------------------------

#define N_TOK 2925
#define DMODEL 1536
#define NHEAD 12
#define HDIM 128

typedef __attribute__((ext_vector_type(8))) __bf16 bf16x8;
typedef __attribute__((ext_vector_type(4))) float floatx4;

#define MFMA(a, b, c) __builtin_amdgcn_mfma_f32_16x16x32_bf16((a), (b), (c), 0, 0, 0)

static __device__ __forceinline__ unsigned short f2bf(float f) {
    unsigned u = __builtin_bit_cast(unsigned, f);
    return (unsigned short)((u + 0x7fffu + ((u >> 16) & 1u)) >> 16);
}

// ---------------------------------------------------------------- convert x
__global__ __launch_bounds__(256) void k_convert_x(const float* __restrict__ x,
                                                   unsigned short* __restrict__ xb, int n) {
    int i = (blockIdx.x * 256 + threadIdx.x) * 4;
    if (i < n) {
        float4 v = *(const float4*)(x + i);
        uint2 o;
        o.x = (unsigned)f2bf(v.x) | ((unsigned)f2bf(v.y) << 16);
        o.y = (unsigned)f2bf(v.z) | ((unsigned)f2bf(v.w) << 16);
        *(uint2*)(xb + i) = o;
    }
}

// ---------------------------------------------- transpose W [k][n] -> Wt [n][k] bf16
__global__ __launch_bounds__(256) void k_transpose_w(const float* __restrict__ W0,
                                                     const float* __restrict__ W1,
                                                     const float* __restrict__ W2,
                                                     const float* __restrict__ W3,
                                                     unsigned short* __restrict__ Wt) {
    __shared__ float tile[32][33];
    const float* W = blockIdx.z == 0 ? W0 : blockIdx.z == 1 ? W1 : blockIdx.z == 2 ? W2 : W3;
    unsigned short* out = Wt + (size_t)blockIdx.z * DMODEL * DMODEL;
    int tx = threadIdx.x, ty = threadIdx.y;           // 32 x 8
    int bx = blockIdx.x * 32, by = blockIdx.y * 32;
#pragma unroll
    for (int i = 0; i < 4; i++)
        tile[ty + 8 * i][tx] = W[(size_t)(by + ty + 8 * i) * DMODEL + bx + tx];
    __syncthreads();
#pragma unroll
    for (int i = 0; i < 4; i++)
        out[(size_t)(bx + ty + 8 * i) * DMODEL + by + tx] = f2bf(tile[tx][ty + 8 * i]);
}

// ------------------------------------------------------------ bf16 MFMA GEMM
// C[M,1536] = A[M,1536](bf16) * W (via pre-transposed Wt[n][k] bf16) + bias.
// 128x128 block tile, 4 waves, each wave 64x64 via 4x4 16x16x32 frags, BK=32.
__global__ __launch_bounds__(256, 2) void k_gemm(const unsigned short* __restrict__ A,
                                                 const unsigned short* __restrict__ BtBase,
                                                 const float* __restrict__ b0,
                                                 const float* __restrict__ b1,
                                                 const float* __restrict__ b2,
                                                 float* __restrict__ Cbase, int M) {
    const int z = blockIdx.z;
    const unsigned short* Bt = BtBase + (size_t)z * DMODEL * DMODEL;
    const float* bias = (z == 0) ? b0 : (z == 1) ? b1 : b2;
    float* C = Cbase + (size_t)z * M * DMODEL;

    __shared__ unsigned short As[128 * 40];   // [row][k] pad 32->40 (80B stride, 2-way max)
    __shared__ unsigned short Bs[128 * 40];   // [n][k]

    const int tid = threadIdx.x;
    const int wave = tid >> 6, lane = tid & 63, quad = lane >> 4, l16 = lane & 15;
    const int wr = wave >> 1, wc = wave & 1;
    const int m0 = blockIdx.y * 128, n0 = blockIdx.x * 128;

    floatx4 acc[4][4] = {};

    for (int k0 = 0; k0 < DMODEL; k0 += 32) {
#pragma unroll
        for (int c = 0; c < 2; c++) {
            int chunk = tid + 256 * c;               // 0..511
            int row = chunk >> 2, col = (chunk & 3) * 8;
            int gm = m0 + row;
            uint4 va = make_uint4(0, 0, 0, 0);
            if (gm < M) va = *(const uint4*)(A + (size_t)gm * DMODEL + k0 + col);
            *(uint4*)&As[row * 40 + col] = va;
            uint4 vb = *(const uint4*)(Bt + (size_t)(n0 + row) * DMODEL + k0 + col);
            *(uint4*)&Bs[row * 40 + col] = vb;
        }
        __syncthreads();

        bf16x8 af[4], bfm[4];
#pragma unroll
        for (int i = 0; i < 4; i++)
            af[i] = *(const bf16x8*)&As[(wr * 64 + i * 16 + l16) * 40 + quad * 8];
#pragma unroll
        for (int j = 0; j < 4; j++)
            bfm[j] = *(const bf16x8*)&Bs[(wc * 64 + j * 16 + l16) * 40 + quad * 8];
#pragma unroll
        for (int i = 0; i < 4; i++)
#pragma unroll
            for (int j = 0; j < 4; j++)
                acc[i][j] = MFMA(af[i], bfm[j], acc[i][j]);
        __syncthreads();
    }

#pragma unroll
    for (int j = 0; j < 4; j++) {
        int cg = n0 + wc * 64 + j * 16 + l16;
        float bv = bias[cg];
#pragma unroll
        for (int i = 0; i < 4; i++) {
            int rbase = m0 + wr * 64 + i * 16 + quad * 4;
#pragma unroll
            for (int r = 0; r < 4; r++) {
                int rg = rbase + r;
                if (rg < M) C[(size_t)rg * DMODEL + cg] = acc[i][j][r] + bv;
            }
        }
    }
}

// ---------------------------------- fused RMSNorm (full 1536) + 3D RoPE + pack
// One block per token. Emits q/k/v bf16 in [head][tok][128] layout.
__global__ __launch_bounds__(256) void k_norm_rope(const float* __restrict__ Qf,
                                                   const float* __restrict__ Kf,
                                                   const float* __restrict__ Vf,
                                                   const float* __restrict__ qsc,
                                                   const float* __restrict__ ksc,
                                                   const float* __restrict__ ft,
                                                   const float* __restrict__ fh,
                                                   const float* __restrict__ fw,
                                                   unsigned short* __restrict__ qb,
                                                   unsigned short* __restrict__ kb,
                                                   unsigned short* __restrict__ vb) {
    const int n = blockIdx.x;
    const int tid = threadIdx.x, wave = tid >> 6, lane = tid & 63;
    const int t_i = n / 225, rem = n % 225, h_i = rem / 15, w_i = rem % 15;

    float2 qv[3], kv[3], vv[3];
    float sq = 0.f, sk = 0.f;
#pragma unroll
    for (int c = 0; c < 3; c++) {
        int p = tid + 256 * c;                     // pair index 0..767
        qv[c] = *(const float2*)(Qf + (size_t)n * DMODEL + 2 * p);
        kv[c] = *(const float2*)(Kf + (size_t)n * DMODEL + 2 * p);
        vv[c] = *(const float2*)(Vf + (size_t)n * DMODEL + 2 * p);
        sq += qv[c].x * qv[c].x + qv[c].y * qv[c].y;
        sk += kv[c].x * kv[c].x + kv[c].y * kv[c].y;
    }
#pragma unroll
    for (int off = 32; off >= 1; off >>= 1) {
        sq += __shfl_xor(sq, off, 64);
        sk += __shfl_xor(sk, off, 64);
    }
    __shared__ float red[2][4];
    if (lane == 0) { red[0][wave] = sq; red[1][wave] = sk; }
    __syncthreads();
    sq = red[0][0] + red[0][1] + red[0][2] + red[0][3];
    sk = red[1][0] + red[1][1] + red[1][2] + red[1][3];
    const float rq = rsqrtf(sq * (1.f / 1536.f) + 1e-6f);
    const float rk = rsqrtf(sk * (1.f / 1536.f) + 1e-6f);

#pragma unroll
    for (int c = 0; c < 3; c++) {
        int p = tid + 256 * c;
        int hd = p >> 6, pl = p & 63, dd = 2 * pl;
        float cs, sn;
        if (pl < 22)      { cs = ft[t_i * 44 + 2 * pl];        sn = ft[t_i * 44 + 2 * pl + 1]; }
        else if (pl < 43) { int pp = pl - 22; cs = fh[h_i * 42 + 2 * pp]; sn = fh[h_i * 42 + 2 * pp + 1]; }
        else              { int pp = pl - 43; cs = fw[w_i * 42 + 2 * pp]; sn = fw[w_i * 42 + 2 * pp + 1]; }
        int hidx = hd * 128 + dd;
        float q0 = qv[c].x * rq * qsc[hidx], q1 = qv[c].y * rq * qsc[hidx + 1];
        float k0 = kv[c].x * rk * ksc[hidx], k1 = kv[c].y * rk * ksc[hidx + 1];
        size_t o = ((size_t)hd * N_TOK + n) * HDIM + dd;
        unsigned qo = (unsigned)f2bf(q0 * cs - q1 * sn) | ((unsigned)f2bf(q0 * sn + q1 * cs) << 16);
        unsigned ko = (unsigned)f2bf(k0 * cs - k1 * sn) | ((unsigned)f2bf(k0 * sn + k1 * cs) << 16);
        unsigned vo = (unsigned)f2bf(vv[c].x) | ((unsigned)f2bf(vv[c].y) << 16);
        *(unsigned*)(qb + o) = qo;
        *(unsigned*)(kb + o) = ko;
        *(unsigned*)(vb + o) = vo;
    }
}

// ------------------------------------------------- flash attention (bf16 MFMA)
// Block = (head, 64 Q rows), 4 waves x 16 rows. KV tiles of 64.
__global__ __launch_bounds__(256, 2) void k_attn(const unsigned short* __restrict__ qb,
                                                 const unsigned short* __restrict__ kb,
                                                 const unsigned short* __restrict__ vb,
                                                 unsigned short* __restrict__ ob) {
    __shared__ unsigned short Qs[64 * 136];   // [qrow][d]   (272B stride: 16B-aligned, 2-way)
    __shared__ unsigned short Ks[64 * 136];   // [key][d]
    __shared__ unsigned short Vs[128 * 72];   // [d][key]    (transposed for B-operand)
    __shared__ unsigned short Ps[4 * 16 * 72];// per-wave P tile [qrow][key]

    const int tid = threadIdx.x, wave = tid >> 6, lane = tid & 63;
    const int quad = lane >> 4, l16 = lane & 15;
    const int head = blockIdx.y;
    const int q0 = blockIdx.x * 64;
    const unsigned short* qh = qb + (size_t)head * N_TOK * HDIM;
    const unsigned short* kh = kb + (size_t)head * N_TOK * HDIM;
    const unsigned short* vh = vb + (size_t)head * N_TOK * HDIM;

    // stage Q (64 x 128)
#pragma unroll
    for (int c = 0; c < 4; c++) {
        int chunk = tid + 256 * c;                 // 0..1023
        int row = chunk >> 4, col = (chunk & 15) * 8;
        int g = q0 + row;
        uint4 v = make_uint4(0, 0, 0, 0);
        if (g < N_TOK) v = *(const uint4*)(qh + (size_t)g * HDIM + col);
        *(uint4*)&Qs[row * 136 + col] = v;
    }

    floatx4 oacc[8] = {};
    float m_r[4] = {-1e30f, -1e30f, -1e30f, -1e30f};
    float l_r[4] = {0.f, 0.f, 0.f, 0.f};
    const float scale = 0.08838834764831845f;      // 1/sqrt(128)

    for (int k0 = 0; k0 < N_TOK; k0 += 64) {
        // stage K (64 x 128)
#pragma unroll
        for (int c = 0; c < 4; c++) {
            int chunk = tid + 256 * c;
            int row = chunk >> 4, col = (chunk & 15) * 8;
            int g = k0 + row;
            uint4 v = make_uint4(0, 0, 0, 0);
            if (g < N_TOK) v = *(const uint4*)(kh + (size_t)g * HDIM + col);
            *(uint4*)&Ks[row * 136 + col] = v;
        }
        // stage V transposed: Vs[d][key]
        {
            int key = tid & 63;
            int g = k0 + key;
#pragma unroll
            for (int c = 0; c < 4; c++) {
                int d0 = (tid >> 6) * 8 + 32 * c;
                uint4 v = make_uint4(0, 0, 0, 0);
                if (g < N_TOK) v = *(const uint4*)(vh + (size_t)g * HDIM + d0);
                unsigned short e[8];
                e[0] = v.x & 0xffff; e[1] = v.x >> 16;
                e[2] = v.y & 0xffff; e[3] = v.y >> 16;
                e[4] = v.z & 0xffff; e[5] = v.z >> 16;
                e[6] = v.w & 0xffff; e[7] = v.w >> 16;
#pragma unroll
                for (int i = 0; i < 8; i++) Vs[(d0 + i) * 72 + key] = e[i];
            }
        }
        __syncthreads();

        // S = Q K^T  (wave's 16 rows x 64 keys)
        floatx4 sa[4] = {};
#pragma unroll
        for (int ks = 0; ks < 4; ks++) {
            bf16x8 aq = *(const bf16x8*)&Qs[(wave * 16 + l16) * 136 + ks * 32 + quad * 8];
#pragma unroll
            for (int j = 0; j < 4; j++) {
                bf16x8 bkf = *(const bf16x8*)&Ks[(j * 16 + l16) * 136 + ks * 32 + quad * 8];
                sa[j] = MFMA(aq, bkf, sa[j]);
            }
        }

        // online softmax update
        bool valid[4];
        float sv[4][4];
#pragma unroll
        for (int j = 0; j < 4; j++) {
            valid[j] = (k0 + j * 16 + l16) < N_TOK;
#pragma unroll
            for (int r = 0; r < 4; r++) sv[j][r] = sa[j][r] * scale;
        }
        float alpha[4];
#pragma unroll
        for (int r = 0; r < 4; r++) {
            float x = -1e30f;
#pragma unroll
            for (int j = 0; j < 4; j++) x = fmaxf(x, valid[j] ? sv[j][r] : -1e30f);
#pragma unroll
            for (int off = 8; off >= 1; off >>= 1) x = fmaxf(x, __shfl_xor(x, off, 16));
            float mnew = fmaxf(m_r[r], x);
            alpha[r] = __expf(m_r[r] - mnew);
            m_r[r] = mnew;
        }
        float rsum[4] = {0.f, 0.f, 0.f, 0.f};
#pragma unroll
        for (int j = 0; j < 4; j++)
#pragma unroll
            for (int r = 0; r < 4; r++) {
                float p = valid[j] ? __expf(sv[j][r] - m_r[r]) : 0.f;
                rsum[r] += p;
                Ps[wave * 1152 + (quad * 4 + r) * 72 + j * 16 + l16] = f2bf(p);
            }
#pragma unroll
        for (int r = 0; r < 4; r++) {
            float s = rsum[r];
#pragma unroll
            for (int off = 8; off >= 1; off >>= 1) s += __shfl_xor(s, off, 16);
            l_r[r] = l_r[r] * alpha[r] + s;
        }
#pragma unroll
        for (int jd = 0; jd < 8; jd++)
#pragma unroll
            for (int r = 0; r < 4; r++) oacc[jd][r] *= alpha[r];

        // O += P V   (P from LDS in A-layout, V transposed as B)
#pragma unroll
        for (int ks = 0; ks < 2; ks++) {
            bf16x8 ap = *(const bf16x8*)&Ps[wave * 1152 + l16 * 72 + ks * 32 + quad * 8];
#pragma unroll
            for (int jd = 0; jd < 8; jd++) {
                bf16x8 bvf = *(const bf16x8*)&Vs[(jd * 16 + l16) * 72 + ks * 32 + quad * 8];
                oacc[jd] = MFMA(ap, bvf, oacc[jd]);
            }
        }
        __syncthreads();
    }

    // epilogue: O /= l, store bf16 to [tok][head*128+d]
#pragma unroll
    for (int r = 0; r < 4; r++) {
        int g = q0 + wave * 16 + quad * 4 + r;
        if (g < N_TOK) {
            float inv = 1.f / l_r[r];
#pragma unroll
            for (int jd = 0; jd < 8; jd++)
                ob[(size_t)g * DMODEL + head * HDIM + jd * 16 + l16] = f2bf(oacc[jd][r] * inv);
        }
    }
}

// ---------------------------------------------------------------------------
extern "C" void kernel_launch(void* const* d_in, const int* in_sizes, int n_in,
                              void* d_out, int out_size, void* d_ws, size_t ws_size,
                              hipStream_t stream) {
    const float* x   = (const float*)d_in[0];
    const float* Wq  = (const float*)d_in[1];
    const float* bq  = (const float*)d_in[2];
    const float* Wk  = (const float*)d_in[3];
    const float* bk  = (const float*)d_in[4];
    const float* Wv  = (const float*)d_in[5];
    const float* bv  = (const float*)d_in[6];
    const float* Wo  = (const float*)d_in[7];
    const float* bo  = (const float*)d_in[8];
    const float* qsc = (const float*)d_in[9];
    const float* ksc = (const float*)d_in[10];
    const float* ft  = (const float*)d_in[11];
    const float* fh  = (const float*)d_in[12];
    const float* fw  = (const float*)d_in[13];

    char* ws = (char*)d_ws;
    unsigned short* xb   = (unsigned short*)ws; ws += (size_t)N_TOK * DMODEL * 2;          // 8,985,600
    unsigned short* Wt   = (unsigned short*)ws; ws += (size_t)4 * DMODEL * DMODEL * 2;     // 18,874,368
    float*          QKVf = (float*)ws;          ws += (size_t)3 * N_TOK * DMODEL * 4;      // 53,913,600
    unsigned short* qkvb = (unsigned short*)ws; ws += (size_t)3 * N_TOK * DMODEL * 2;      // 26,956,800
    unsigned short* ab   = (unsigned short*)ws; ws += (size_t)N_TOK * DMODEL * 2;          // 8,985,600

    float* Qf = QKVf;
    float* Kf = QKVf + (size_t)N_TOK * DMODEL;
    float* Vf = QKVf + (size_t)2 * N_TOK * DMODEL;
    unsigned short* qbp = qkvb;
    unsigned short* kbp = qkvb + (size_t)N_TOK * DMODEL;
    unsigned short* vbp = qkvb + (size_t)2 * N_TOK * DMODEL;

    const int nelem = N_TOK * DMODEL;  // 4,492,800 (divisible by 4)
    k_convert_x<<<(nelem / 4 + 255) / 256, 256, 0, stream>>>(x, xb, nelem);
    k_transpose_w<<<dim3(48, 48, 4), dim3(32, 8), 0, stream>>>(Wq, Wk, Wv, Wo, Wt);
    k_gemm<<<dim3(12, 23, 3), 256, 0, stream>>>(xb, Wt, bq, bk, bv, QKVf, N_TOK);
    k_norm_rope<<<N_TOK, 256, 0, stream>>>(Qf, Kf, Vf, qsc, ksc, ft, fh, fw, qbp, kbp, vbp);
    k_attn<<<dim3(46, NHEAD), 256, 0, stream>>>(qbp, kbp, vbp, ab);
    k_gemm<<<dim3(12, 23, 1), 256, 0, stream>>>(ab, Wt + (size_t)3 * DMODEL * DMODEL,
                                                bo, bo, bo, (float*)d_out, N_TOK);
}